// Round 13
// baseline (72.425 us; speedup 1.0000x reference)
//
#include <hip/hip_runtime.h>
#include <hip/hip_bf16.h>

#define N2 16384
#define D  128
#define PANEL 16384                       // bytes per 128x128 fp8 panel
#define SQC1 1.69864360258810896f         // sqrt(2*log2(e)), folded into zq
#define LN2  0.69314718055994530942f

typedef float f32x4 __attribute__((ext_vector_type(4)));

#if __has_builtin(__builtin_amdgcn_exp2f)
#define EXP2(x) __builtin_amdgcn_exp2f(x)
#else
#define EXP2(x) exp2f(x)
#endif

// f32 -> OCP e4m3fn, RNE. |f| <= ~1.8 here (no overflow path). (R8-proven)
__device__ __forceinline__ unsigned char f2e4m3(float f) {
    union { float f; unsigned u; } v; v.f = f;
    unsigned s = (v.u >> 24) & 0x80;
    int e = (int)((v.u >> 23) & 255) - 127;
    unsigned m = v.u & 0x7fffff;
    if (e < -10) return (unsigned char)s;
    if (e >= -6) {
        unsigned r = m + 0x7ffff + ((m >> 20) & 1);
        unsigned mm = r >> 20;
        int E = e;
        if (mm >= 8) { mm = 0; E += 1; }
        return (unsigned char)(s | ((E + 7) << 3) | (mm & 7));
    }
    float a = fabsf(f) * 512.0f;
    int n = (int)rintf(a);
    return (unsigned char)(s | n);
}

// e4m3fn -> f32 (no NaN inputs produced by f2e4m3 here)
__device__ __forceinline__ float e4m3f(unsigned v) {
    unsigned s = v >> 7, e = (v >> 3) & 15, m = v & 7;
    float f;
    if (e) { union { unsigned u; float g; } x; x.u = ((e + 120) << 23) | (m << 20); f = x.g; }
    else   f = (float)m * 0.001953125f;   // m * 2^-9
    return s ? -f : f;
}

// stage one 16KB fp8 panel global->LDS via global_load_lds width=16 (4 instrs).
// LDS dest linear; XOR swizzle pre-applied to the GLOBAL source (involution
// on 16B granules); reads use byte ^ ((row&7)<<4), row = byte>>7. (rule #21)
__device__ __forceinline__ void stage16(const char* __restrict__ g,
                                        char* lds, int tid) {
    const int wid = tid >> 6, lane = tid & 63;
    #pragma unroll
    for (int i = 0; i < 4; ++i) {
        int off = (wid << 12) + (i << 10) + (lane << 4);
        int src = off ^ (((off >> 7) & 7) << 4);
        __builtin_amdgcn_global_load_lds(
            (const __attribute__((address_space(1))) unsigned*)(g + src),
            (__attribute__((address_space(3))) unsigned*)(lds + (wid << 12) + (i << 10)),
            16, 0, 0);
    }
}

// ---------- kernel 1: L2-normalize -> fp8 sqrt(C1)*zn; zero rowsum/out ----------
__global__ void k_norm(const float* __restrict__ z, unsigned char* __restrict__ zq,
                       float* __restrict__ rowsum, float* __restrict__ out) {
    if (blockIdx.x < 64) rowsum[blockIdx.x * 256 + threadIdx.x] = 0.f;
    if (blockIdx.x == 64 && threadIdx.x == 0) out[0] = 0.f;
    int row  = blockIdx.x * 4 + (threadIdx.x >> 6);
    int lane = threadIdx.x & 63;
    const float2 v = ((const float2*)(z + (size_t)row * D))[lane];
    float ss = v.x * v.x + v.y * v.y;
    #pragma unroll
    for (int m = 1; m < 64; m <<= 1) ss += __shfl_xor(ss, m);
    float inv = SQC1 / fmaxf(sqrtf(ss), 1e-12f);
    unsigned short o = (unsigned short)f2e4m3(v.x * inv)
                     | ((unsigned short)f2e4m3(v.y * inv) << 8);
    ((unsigned short*)(zq + (size_t)row * D))[lane] = o;
}

// ---------- kernel 2: symmetric fused sim GEMM (fp8) + exp row/col sums ----------
// block (c, ti): s in [11c, ...); jt=(ti+s)&127. A(ti) fp8 frags in regs (32 VGPR);
// B panels TRIPLE-buffered in 3x16KB -> ONE barrier per tile:
//   tile t: {vmcnt(exact); barrier; stage B(t+2)->buf[(t+2)%3]; ds_read buf[t%3];
//            MFMA; epilogue(exp + 4 col atomics, uniform count)}
// Safety: stage(t+2) is issued after barrier(t); buf[(t+2)%3]'s readers ran in
// tile t-1 and their ds_reads were consumed by MFMAs before epilogue(t-1),
// hence complete before barrier(t). vmcnt bookkeeping (4 stage + 4 atomics
// per tile, in-order retire): t=0 -> 4, t=1 or nt-1 -> 8, else 12 -- drains
// B(t) only, never fresh atomics (R8's bug, fixed).
__global__ __launch_bounds__(256, 3)
void k_sim(const unsigned char* __restrict__ zq, float* __restrict__ rowsum) {
    __shared__ char ls[3 * PANEL];        // 48KB triple buffer -> 3 blocks/CU

    const int tileI = blockIdx.y;
    const int c = blockIdx.x;
    const int sLo = c * 11;
    const int nt = (c < 5) ? 11 : ((tileI < 64) ? 10 : 9);

    const int tid  = threadIdx.x;
    const int lane = tid & 63, wid = tid >> 6;
    const int wr = wid >> 1, wc = wid & 1;          // 2x2 waves: 64x64 each
    const int l16 = lane & 15, lg = lane >> 4;
    const char* zb = (const char*)zq;

    // prologue: A(ti) -> buf0, pull fp8 A fragments (2 regs each) to registers
    stage16(zb + (size_t)tileI * PANEL, ls, tid);
    asm volatile("s_waitcnt vmcnt(0)" ::: "memory");
    __builtin_amdgcn_s_barrier();

    long af[4][4];                                     // [kk][m], 32 VGPR total
    #pragma unroll
    for (int kk = 0; kk < 4; ++kk)
        #pragma unroll
        for (int m = 0; m < 4; ++m) {
            int row = wr * 64 + m * 16 + l16;
            int d = row * 128 + kk * 32 + lg * 8;
            af[kk][m] = *(const long*)(ls + (d ^ ((row & 7) << 4)));
        }
    asm volatile("s_waitcnt lgkmcnt(0)" ::: "memory");
    __builtin_amdgcn_s_barrier();                      // buf0 free for B

    stage16(zb + (size_t)((tileI + sLo) & 127) * PANEL, ls, tid);           // B(0)
    stage16(zb + (size_t)((tileI + sLo + 1) & 127) * PANEL, ls + PANEL, tid); // B(1)

    float rs[4][4];
    #pragma unroll
    for (int m = 0; m < 4; ++m)
        #pragma unroll
        for (int r = 0; r < 4; ++r) rs[m][r] = 0.f;

    int cur = 0;                                       // t % 3
    for (int t = 0; t < nt; ++t) {
        const int s  = sLo + t;
        const int jt = (tileI + s) & 127;

        // exact counted drain of B(t); newer stages/atomics stay in flight
        if (t == 0)                    { asm volatile("s_waitcnt vmcnt(4)"  ::: "memory"); }
        else if (t == 1 || t == nt - 1){ asm volatile("s_waitcnt vmcnt(8)"  ::: "memory"); }
        else                           { asm volatile("s_waitcnt vmcnt(12)" ::: "memory"); }
        __builtin_amdgcn_s_barrier();                  // the ONLY barrier per tile

        char* rbuf = ls + (cur << 14);
        if (t + 2 < nt) {
            int nxt = cur + 2; if (nxt >= 3) nxt -= 3;
            stage16(zb + (size_t)((tileI + s + 2) & 127) * PANEL, ls + (nxt << 14), tid);
        }

        // K-loop: per-kk B frags (8 transient regs), 16 MFMA each
        f32x4 acc[4][4];
        __builtin_amdgcn_s_setprio(1);
        #pragma unroll
        for (int kk = 0; kk < 4; ++kk) {
            long bk[4];
            #pragma unroll
            for (int n = 0; n < 4; ++n) {
                int row = wc * 64 + n * 16 + l16;
                int d = row * 128 + kk * 32 + lg * 8;
                bk[n] = *(const long*)(rbuf + (d ^ ((row & 7) << 4)));
            }
            #pragma unroll
            for (int m = 0; m < 4; ++m)
                #pragma unroll
                for (int n = 0; n < 4; ++n)
                    acc[m][n] = __builtin_amdgcn_mfma_f32_16x16x32_fp8_fp8(
                        af[kk][m], bk[n],
                        (kk == 0) ? f32x4{0.f, 0.f, 0.f, 0.f} : acc[m][n], 0, 0, 0);
        }
        __builtin_amdgcn_s_setprio(0);

        // epilogue: e = exp2(acc) = exp(sim); uniform 4-atomic col flush
        float cs[4] = {0.f, 0.f, 0.f, 0.f};
        if (s == 0) {
            // diagonal tile: mask self-sim, row sums only (cs stays 0)
            #pragma unroll
            for (int m = 0; m < 4; ++m)
                #pragma unroll
                for (int r = 0; r < 4; ++r) {
                    int li = wr * 64 + m * 16 + lg * 4 + r;
                    float a = 0.f;
                    #pragma unroll
                    for (int n = 0; n < 4; ++n) {
                        int lj = wc * 64 + n * 16 + l16;
                        float e = EXP2(acc[m][n][r]);
                        a += (li == lj) ? 0.f : e;
                    }
                    rs[m][r] += a;
                }
        } else {
            #pragma unroll
            for (int m = 0; m < 4; ++m)
                #pragma unroll
                for (int r = 0; r < 4; ++r) {
                    float a = 0.f;
                    #pragma unroll
                    for (int n = 0; n < 4; ++n) {
                        float e = EXP2(acc[m][n][r]);
                        a += e;
                        cs[n] += e;
                    }
                    rs[m][r] += a;
                }
        }
        // column flush (always 4 atomic instrs -> vmcnt count is uniform)
        #pragma unroll
        for (int n = 0; n < 4; ++n) {
            float v = cs[n];
            v += __shfl_xor(v, 16);
            v += __shfl_xor(v, 32);
            if (lg == 0)
                atomicAdd(&rowsum[jt * 128 + wc * 64 + n * 16 + l16], v);
        }
        cur = (cur == 2) ? 0 : cur + 1;
    }

    // row-sum flush: reduce across 16 column-lanes, one atomic per row
    #pragma unroll
    for (int m = 0; m < 4; ++m)
        #pragma unroll
        for (int r = 0; r < 4; ++r) {
            float v = rs[m][r];
            v += __shfl_xor(v, 1);
            v += __shfl_xor(v, 2);
            v += __shfl_xor(v, 4);
            v += __shfl_xor(v, 8);
            if (l16 == 0)
                atomicAdd(&rowsum[tileI * 128 + wr * 64 + m * 16 + lg * 4 + r], v);
        }
}

// ---------- kernel 3: fused loss + mean (fp8 pos-dot) ----------
// mean loss = (1/N2) * [ sum_i ln(rowsum_i) - ln2 * sum_{i,k} zq[i][k]*zq[i^1][k] ]
__global__ void k_loss_reduce(const unsigned char* __restrict__ zq,
                              const float* __restrict__ rowsum,
                              float* __restrict__ out) {
    const int tid = threadIdx.x + blockIdx.x * 256;   // 64 blocks x 256 = 16384
    float p = 0.f;
    const uint4* v16 = (const uint4*)zq;              // 16 fp8 per uint4
    for (int v = tid; v < N2 * D / 16; v += 64 * 256) {
        uint4 a = v16[v];
        uint4 b = v16[v ^ 8];                         // partner row i^1, same k-slice
        const unsigned* aw = (const unsigned*)&a;
        const unsigned* bw = (const unsigned*)&b;
        #pragma unroll
        for (int w = 0; w < 4; ++w)
            #pragma unroll
            for (int j = 0; j < 4; ++j)
                p += e4m3f((aw[w] >> (8 * j)) & 255) * e4m3f((bw[w] >> (8 * j)) & 255);
    }
    float part = logf(rowsum[tid]) - LN2 * p;         // exactly one row per thread

    __shared__ float sm[4];
    #pragma unroll
    for (int m = 1; m < 64; m <<= 1) part += __shfl_xor(part, m);
    if ((threadIdx.x & 63) == 0) sm[threadIdx.x >> 6] = part;
    __syncthreads();
    if (threadIdx.x == 0)
        atomicAdd(out, (sm[0] + sm[1] + sm[2] + sm[3]) * (1.0f / (float)N2));
}

extern "C" void kernel_launch(void* const* d_in, const int* in_sizes, int n_in,
                              void* d_out, int out_size, void* d_ws, size_t ws_size,
                              hipStream_t stream) {
    const float* z = (const float*)d_in[0];
    float* out = (float*)d_out;

    unsigned char* zq = (unsigned char*)d_ws;                         // 2 MiB fp8
    float* rowsum = (float*)((char*)d_ws + (size_t)N2 * D);           // 64 KiB

    k_norm<<<N2 / 4, 256, 0, stream>>>(z, zq, rowsum, out);
    dim3 grid(6, 128);                                                // s-chunks x i-tiles
    k_sim<<<grid, 256, 0, stream>>>(zq, rowsum);
    k_loss_reduce<<<64, 256, 0, stream>>>(zq, rowsum, out);
}